// Round 8
// baseline (674.339 us; speedup 1.0000x reference)
//
#include <hip/hip_runtime.h>
#include <hip/hip_bf16.h>
#include <stdint.h>

// ---------------------------------------------------------------------------
// Round 11: wave-chain at 15 WGs/CU, all-verified LDS patterns + valueL0.
//  - r10's mid_pairQ (half-wave predicated Z write -- prime suspect for the
//    r10 correctness failure) replaced by mid_pair32: pure parameterization
//    of the r8/r9-verified mid_pair (32-col chunks, full-exec epiW write to
//    Z[32][36], KSTEPS=2 L2 steps). No novel LDS pattern.
//  - valueL0 kept (layout-proof: same fragment construction as verified
//    path); this round is its bisect test. It also kills r9's aG spill by
//    removing the value-chain staging regs.
//  - LDS: X[32][132] 8448 + Z[32][36] 2304 + mask 128 = 10880 -> 15 WGs/CU.
//  - __launch_bounds__(64,4): cap 128; peak live ~120 (no staging array).
// Same fragment-ordered ws layout + prep kernel as r4-r9 (verified).
// ---------------------------------------------------------------------------

typedef __attribute__((ext_vector_type(8))) short short8_t;
typedef __attribute__((ext_vector_type(16))) float f32x16;

#define ROWS 32
#define NWG  4096            // 131072 / 32
#define NTHR 64

#define SA 132               // X row stride (shorts): 264 B (r9-verified, 0 conflicts)
#define SZ 36                // Z row stride (shorts): 72 B

// LDS layout (bytes)
#define OFF_X 0              // [32][132] shorts = 8448 (staging / activations)
#define OFF_Z 8448           // [32][36]  shorts = 2304 (32-col chunk buf)
#define OFF_M 10752          // 32 floats = 128
#define LDS_TOTAL 10880      // 163840/10880 = 15 WGs/CU

__device__ __forceinline__ short f2bf(float f) {
  union { float f; uint32_t u; } v; v.f = f;
  uint32_t r = (v.u + 0x7FFFu + ((v.u >> 16) & 1u)) >> 16;  // RNE
  return (short)r;
}

// ---- MFMA block: A from LDS (row = lane&31), B coalesced from fragment-
// ordered global. Weight elem off = ((cb*KT16 + ks)<<9) + lane*8 + j
//   -> logical n = cb*32 + (lane&31), k = ks*16 + (lane>>5)*8 + j.
// A: lane n32 -> act row n32, k(local) = ks*16 + q32*8 + j; ks0 offsets only
// B, so partial-K passes read A with local k. A and B fragments use the same
// (lane,j)->k construction, so correctness is invariant to the HW-internal
// k-permutation.
template <int KT16, int KSTEPS, int CT>
__device__ __forceinline__ void gemmW(const short* actin, int Sin,
                                      const short* __restrict__ wsB, int ks0, int cb0,
                                      f32x16 (&acc)[CT], int lane) {
  const int n32 = lane & 31, q32 = lane >> 5;
#pragma unroll
  for (int ks = 0; ks < KSTEPS; ++ks) {
    const int kl = ks * 16 + q32 * 8;
    short8_t b[CT];
#pragma unroll
    for (int ct = 0; ct < CT; ++ct)
      b[ct] = *(const short8_t*)(wsB + (((cb0 + ct) * KT16 + ks0 + ks) << 9) + lane * 8);
    const short8_t a = *(const short8_t*)(actin + n32 * Sin + kl);
#pragma unroll
    for (int ct = 0; ct < CT; ++ct)
      acc[ct] = __builtin_amdgcn_mfma_f32_32x32x16_bf16(a, b[ct], acc[ct], 0, 0, 0);
  }
}

// Same, but A-fragments from registers (aR[ks]), K=128 fixed (8 steps).
template <int KT16, int CT>
__device__ __forceinline__ void gemmRA(const short8_t (&aR)[8],
                                       const short* __restrict__ wsB, int cb0,
                                       f32x16 (&acc)[CT], int lane) {
#pragma unroll
  for (int ks = 0; ks < 8; ++ks) {
    short8_t b[CT];
#pragma unroll
    for (int ct = 0; ct < CT; ++ct)
      b[ct] = *(const short8_t*)(wsB + (((cb0 + ct) * KT16 + ks) << 9) + lane * 8);
#pragma unroll
    for (int ct = 0; ct < CT; ++ct)
      acc[ct] = __builtin_amdgcn_mfma_f32_32x32x16_bf16(aR[ks], b[ct], acc[ct], 0, 0, 0);
  }
}

// C/D layout (verified m74/m101): col = lane&31, row = (reg&3)+8*(reg>>2)+4*(lane>>5)
template <int CT, int ACTF>
__device__ __forceinline__ void epiW(f32x16 (&acc)[CT], short* actout, int Sout,
                                     const float* __restrict__ bias, int c0,
                                     int n32, int q32) {
#pragma unroll
  for (int ct = 0; ct < CT; ++ct) {
    const int c = c0 + ct * 32 + n32;
    const float bv = bias[c];
#pragma unroll
    for (int reg = 0; reg < 16; ++reg) {
      const int r = (reg & 3) + 8 * (reg >> 2) + 4 * q32;
      float v = acc[ct][reg] + bv;
      if (ACTF == 1) v = fmaxf(v, 0.f);
      actout[r * Sout + c] = f2bf(v);
    }
  }
}

// ---- input staging: one chunk = 32 rows x 128 cols fp32 -> bf16 LDS -------
// Split into two 16-row groups to cap live staging regs at ~32.
// mmode: 0 none, 1 init maskacc, 2 accumulate (mask = row-sum of h0).
template <bool MASKA>
__device__ __forceinline__ void stage_chunk(const float* __restrict__ src, int row0,
                                            int colbase, short* X, float* maskacc,
                                            int mmode, int lane) {
  const int c4 = lane & 31, rh = lane >> 5;
#pragma unroll
  for (int g = 0; g < 2; ++g) {
    float4 v[8];
#pragma unroll
    for (int it = 0; it < 8; ++it)
      v[it] = *(const float4*)(src + (size_t)(row0 + g * 16 + 2 * it + rh) * 256 + colbase + c4 * 4);
#pragma unroll
    for (int it = 0; it < 8; ++it) {
      const int r = g * 16 + 2 * it + rh;
      short4 pk; pk.x = f2bf(v[it].x); pk.y = f2bf(v[it].y); pk.z = f2bf(v[it].z); pk.w = f2bf(v[it].w);
      *(short4*)(X + r * SA + c4 * 4) = pk;
      if (MASKA && mmode) {
        float s = v[it].x + v[it].y + v[it].z + v[it].w;
        s += __shfl_down(s, 16, 32);
        s += __shfl_down(s, 8, 32);
        s += __shfl_down(s, 4, 32);
        s += __shfl_down(s, 2, 32);
        s += __shfl_down(s, 1, 32);
        if (c4 == 0) {
          if (mmode == 1) maskacc[r] = s; else maskacc[r] += s;
        }
      }
    }
  }
}

// Streamed gate first layer (K = NCH*128, N=128 out, CT=4). Chunks kc<splitc
// from src0, else src1. Staging and output both in X (in-place; single-wave
// program order makes read-before-overwrite safe).
template <int NCH, bool MASKA>
__device__ __forceinline__ void streamW(const float* __restrict__ src0,
                                        const float* __restrict__ src1, int splitc,
                                        const short* __restrict__ wsB,
                                        const float* __restrict__ bias,
                                        short* X, float* maskacc,
                                        int row0, int lane) {
  constexpr int KT16 = NCH * 8;
  const int n32 = lane & 31, q32 = lane >> 5;
  f32x16 acc[4];
#pragma unroll
  for (int ct = 0; ct < 4; ++ct) acc[ct] = (f32x16)(0.f);
#pragma unroll
  for (int kc = 0; kc < NCH; ++kc) {
    const bool lo = (kc < splitc);
    const float* src = lo ? src0 : src1;
    const int colbase = (lo ? kc : kc - splitc) * 128;
    const int mm = MASKA ? (kc == 0 ? 1 : (lo ? 2 : 0)) : 0;
    stage_chunk<MASKA>(src, row0, colbase, X, maskacc, mm, lane);
    gemmW<KT16, 8, 4>(X, SA, wsB, kc * 8, 0, acc, lane);
  }
  epiW<4, 1>(acc, X, SA, bias, 0, n32, q32);
}

// value-L0: K=256, N=128, A-fragments read DIRECTLY from global hT (fp32,
// L2/L3-warm from the gate stream). Lane n32 reads 32B of row row0+n32 per
// ks; fragment construction identical to the verified LDS path.
__device__ __forceinline__ void valueL0(const float* __restrict__ hT,
                                        const short* __restrict__ wsB,   // KT16=16
                                        const float* __restrict__ bias,
                                        short* X, int row0, int lane) {
  const int n32 = lane & 31, q32 = lane >> 5;
  f32x16 acc[4];
#pragma unroll
  for (int ct = 0; ct < 4; ++ct) acc[ct] = (f32x16)(0.f);
  const float* rowp = hT + (size_t)(row0 + n32) * 256 + q32 * 8;
#pragma unroll
  for (int ks = 0; ks < 16; ++ks) {
    const float4 u0 = *(const float4*)(rowp + ks * 16);
    const float4 u1 = *(const float4*)(rowp + ks * 16 + 4);
    short8_t a;
    a[0] = f2bf(u0.x); a[1] = f2bf(u0.y); a[2] = f2bf(u0.z); a[3] = f2bf(u0.w);
    a[4] = f2bf(u1.x); a[5] = f2bf(u1.y); a[6] = f2bf(u1.z); a[7] = f2bf(u1.w);
    short8_t b[4];
#pragma unroll
    for (int ct = 0; ct < 4; ++ct)
      b[ct] = *(const short8_t*)(wsB + ((ct * 16 + ks) << 9) + lane * 8);
#pragma unroll
    for (int ct = 0; ct < 4; ++ct)
      acc[ct] = __builtin_amdgcn_mfma_f32_32x32x16_bf16(a, b[ct], acc[ct], 0, 0, 0);
  }
  epiW<4, 1>(acc, X, SA, bias, 0, n32, q32);
}

// Layer pair: (K=128 -> N=256, ReLU) then (K=256 -> N=128, ReLU), the 256-wide
// intermediate processed in eight 32-col chunks through Z[32][36] (acc-chain).
// Pure parameterization of the r8/r9-verified mid_pair (full-exec epiW write).
__device__ __forceinline__ void mid_pair32(short* A, short* Z,
                                           const short* __restrict__ ws1,
                                           const float* __restrict__ b1,
                                           const short* __restrict__ ws2,
                                           const float* __restrict__ b2,
                                           int lane) {
  const int n32 = lane & 31, q32 = lane >> 5;
  f32x16 acc2[4];
#pragma unroll
  for (int ct = 0; ct < 4; ++ct) acc2[ct] = (f32x16)(0.f);
#pragma unroll
  for (int q = 0; q < 8; ++q) {
    f32x16 a1[1];
    a1[0] = (f32x16)(0.f);
    gemmW<8, 8, 1>(A, SA, ws1, 0, q, a1, lane);             // L1 cols q*32..+31
    epiW<1, 1>(a1, Z, SZ, b1 + q * 32, 0, n32, q32);        // local cols 0..31
    gemmW<16, 2, 4>(Z, SZ, ws2, q * 2, 0, acc2, lane);      // L2 k-slice q*32..
  }
  epiW<4, 1>(acc2, A, SA, b2, 0, n32, q32);                 // overwrite A (reads done)
}

// Fused last layers: per column-quarter, gate-L3 (sigmoid, A from regs) and
// val-L3 (A from LDS) together, then mask*gate*val reduced + atomicAdd.
__device__ __forceinline__ void final_fuse(const short8_t (&aG)[8], const short* Av,
                                           const short* __restrict__ wsg,
                                           const float* __restrict__ bg,
                                           const short* __restrict__ wsv,
                                           const float* __restrict__ bv,
                                           const float* maskacc, float* __restrict__ out,
                                           int bidx, int lane) {
  const int n32 = lane & 31, q32 = lane >> 5;
#pragma unroll
  for (int q = 0; q < 4; ++q) {
    f32x16 ag[2]; ag[0] = (f32x16)(0.f); ag[1] = (f32x16)(0.f);
    gemmRA<8, 2>(aG, wsg, q * 2, ag, lane);
    f32x16 av[2]; av[0] = (f32x16)(0.f); av[1] = (f32x16)(0.f);
    gemmW<8, 8, 2>(Av, SA, wsv, 0, q * 2, av, lane);
#pragma unroll
    for (int ct = 0; ct < 2; ++ct) {
      const int c = q * 64 + ct * 32 + n32;
      const float gb = bg[c], ob = bv[c];
      float s = 0.f;
#pragma unroll
      for (int reg = 0; reg < 16; ++reg) {
        const int r = (reg & 3) + 8 * (reg >> 2) + 4 * q32;
        if (maskacc[r] > 0.f) {
          const float g = 1.f / (1.f + __expf(-(ag[ct][reg] + gb)));
          s += g * (av[ct][reg] + ob);
        }
      }
      s += __shfl_down(s, 32);
      if (lane < 32) atomicAdd(out + bidx * 256 + c, s);
    }
  }
}

__global__ __launch_bounds__(NTHR, 4)
void readout_main(const float* __restrict__ h0, const float* __restrict__ hT,
                  const short* __restrict__ ws,
                  const float* __restrict__ gb0, const float* __restrict__ gb1,
                  const float* __restrict__ gb2, const float* __restrict__ gb3,
                  const float* __restrict__ ob0, const float* __restrict__ ob1,
                  const float* __restrict__ ob2, const float* __restrict__ ob3,
                  float* __restrict__ out) {
  __shared__ __align__(16) char smem[LDS_TOTAL];
  short* X = (short*)(smem + OFF_X);       // staging / activations
  short* Z = (short*)(smem + OFF_Z);       // 32-col chunk buffer
  float* maskacc = (float*)(smem + OFF_M);

  const int lane = threadIdx.x;            // 64-thread WG = 1 wave
  const int row0 = blockIdx.x * ROWS;
  const int bidx = row0 >> 8;              // 8 WGs per batch
  const int n32 = lane & 31, q32 = lane >> 5;

  // gate chain: [h0; hT] (K=512) -> 128 -> 256 -> 128, result in X
  streamW<4, true>(h0, hT, 2, ws + 0, gb0, X, maskacc, row0, lane);
  mid_pair32(X, Z, ws + 65536, gb1, ws + 98304, gb2, lane);
  // park A_g in regs as pre-formed MFMA A-fragments (8 x ds_read_b128)
  short8_t aG[8];
#pragma unroll
  for (int ks = 0; ks < 8; ++ks)
    aG[ks] = *(const short8_t*)(X + n32 * SA + ks * 16 + q32 * 8);
  // value chain: hT (K=256, direct-global A-frags) -> 128 -> 256 -> 128 in X
  valueL0(hT, ws + 163840, ob0, X, row0, lane);
  mid_pair32(X, Z, ws + 196608, ob1, ws + 229376, ob2, lane);
  // fused gate-L3 (sigmoid, regs) + val-L3 (LDS) + mask*gate*val reduce
  final_fuse(aG, X, ws + 131072, gb3, ws + 262144, ob3, maskacc, out, bidx, lane);
}

// ---- prep: weights fp32[K][N] -> bf16 fragment-ordered; zero out -----------
// ws elem off = layer_off + ((cb*(K/16) + ks)<<9) + lanei*8 + j
//   with n = cb*32 + (lanei&31), k = ks*16 + (lanei>>5)*8 + j.
__global__ void prep(const float* __restrict__ W0, const float* __restrict__ W1,
                     const float* __restrict__ W2, const float* __restrict__ W3,
                     const float* __restrict__ W4, const float* __restrict__ W5,
                     const float* __restrict__ W6, const float* __restrict__ W7,
                     short* __restrict__ ws, float* __restrict__ out) {
  const int l = blockIdx.y;
  const int le = blockIdx.x * 256 + threadIdx.x;    // < 65536
  if (l == 1) { out[le] = 0.f; out[le + 65536] = 0.f; }
  int K, N, off; const float* W;
  switch (l) {
    case 0:  K = 512; N = 128; off = 0;      W = W0; break;
    case 1:  K = 128; N = 256; off = 65536;  W = W1; break;
    case 2:  K = 256; N = 128; off = 98304;  W = W2; break;
    case 3:  K = 128; N = 256; off = 131072; W = W3; break;
    case 4:  K = 256; N = 128; off = 163840; W = W4; break;
    case 5:  K = 128; N = 256; off = 196608; W = W5; break;
    case 6:  K = 256; N = 128; off = 229376; W = W6; break;
    default: K = 128; N = 256; off = 262144; W = W7; break;
  }
  if (le >= K * N) return;
  const int j = le & 7;
  const int lanei = (le >> 3) & 63;
  const int blk = le >> 9;
  const int kt16 = K >> 4;
  const int ks = blk % kt16, cb = blk / kt16;
  const int n = cb * 32 + (lanei & 31);
  const int k = ks * 16 + (lanei >> 5) * 8 + j;
  ws[off + le] = f2bf(W[k * N + n]);    // coalesced write, gathered read
}

extern "C" void kernel_launch(void* const* d_in, const int* in_sizes, int n_in,
                              void* d_out, int out_size, void* d_ws, size_t ws_size,
                              hipStream_t stream) {
  const float* h0  = (const float*)d_in[0];
  const float* hT  = (const float*)d_in[1];
  const float* gW0 = (const float*)d_in[2];  const float* gb0 = (const float*)d_in[3];
  const float* gW1 = (const float*)d_in[4];  const float* gb1 = (const float*)d_in[5];
  const float* gW2 = (const float*)d_in[6];  const float* gb2 = (const float*)d_in[7];
  const float* gW3 = (const float*)d_in[8];  const float* gb3 = (const float*)d_in[9];
  const float* oW0 = (const float*)d_in[10]; const float* ob0 = (const float*)d_in[11];
  const float* oW1 = (const float*)d_in[12]; const float* ob1 = (const float*)d_in[13];
  const float* oW2 = (const float*)d_in[14]; const float* ob2 = (const float*)d_in[15];
  const float* oW3 = (const float*)d_in[16]; const float* ob3 = (const float*)d_in[17];
  float* out = (float*)d_out;
  short* ws  = (short*)d_ws;   // 589824 B

  prep<<<dim3(256, 8), 256, 0, stream>>>(gW0, gW1, gW2, gW3, oW0, oW1, oW2, oW3, ws, out);
  readout_main<<<NWG, NTHR, 0, stream>>>(h0, hT, ws,
                                         gb0, gb1, gb2, gb3,
                                         ob0, ob1, ob2, ob3, out);
}

// Round 9
// 495.333 us; speedup vs baseline: 1.3614x; 1.3614x over previous
//
#include <hip/hip_runtime.h>
#include <hip/hip_bf16.h>
#include <stdint.h>

// ---------------------------------------------------------------------------
// Round 12: B-reuse=2 at 12 waves/CU, spill-proof. r4 skeleton (64-row tile,
// 4 waves, RT=2, B2 materialized, verified barriers) with:
//  - every N=256 consumer split into two CT=1 passes (mid-L1 -> B2, gate-L3,
//    val-L3): max acc 64 -> 32 regs. Same MFMA count / B-traffic / barriers
//    (both passes write disjoint B2 cols before one barrier).
//  - __launch_bounds__(256,3): cap 170 (the proven-safe cap; 128 and below
//    spilled catastrophically in r6/r7b/r11). LDS 52.5 KB -> 3 blocks/CU.
// Peak live ~110-130 < 170 -> no spill predicted (tripwire: WRITE_SIZE).
// ---------------------------------------------------------------------------

typedef __attribute__((ext_vector_type(8))) short short8_t;
typedef __attribute__((ext_vector_type(16))) float f32x16;

#define ROWS 64
#define NWG  2048            // 131072 / 64 exactly
#define NTHR 256

// LDS layout (bytes)
#define PE        (64 * 136)     // one stage buffer, shorts
#define OFF_P     0              // P db: 2 x [64][136] = 34816 B ; alias B2 [64][264] = 33792 B
#define OFF_A     34816          // A [64][136] = 17408 B
#define OFF_MASK  52224          // 64 floats
#define LDS_TOTAL 52480

__device__ __forceinline__ short f2bf(float f) {
  union { float f; uint32_t u; } v; v.f = f;
  uint32_t r = (v.u + 0x7FFFu + ((v.u >> 16) & 1u)) >> 16;  // RNE
  return (short)r;
}
__device__ __forceinline__ float bf2f(short b) {
  union { uint32_t u; float f; } v; v.u = ((uint32_t)(uint16_t)b) << 16;
  return v.f;
}

// ---- MFMA block: A from LDS, B coalesced from fragment-ordered global ------
// Weight layout: elem off = ((cb*KT16 + ks)<<9) + lane*8 + j
//   maps to logical n = cb*32 + (lane&31), k = ks*16 + (lane>>5)*8 + j.
// A: lane n32 -> act row (rt*32+n32), k = ks*16 + q32*8 + j. Dual k-mapping
// matches B's, so any k-permutation cancels in the dot product.
template <int KT16, int KSTEPS, int CT>
__device__ __forceinline__ void gemm32(const short* actin, int Sin,
                                       const short* __restrict__ wsB, int ks0, int cb0,
                                       f32x16 (&acc)[2][CT], int lane) {
  const int n32 = lane & 31, q32 = lane >> 5;
#pragma unroll
  for (int ks = 0; ks < KSTEPS; ++ks) {
    const int kl = ks * 16 + q32 * 8;
    short8_t b[CT];
#pragma unroll
    for (int ct = 0; ct < CT; ++ct)
      b[ct] = *(const short8_t*)(wsB + (((cb0 + ct) * KT16 + ks0 + ks) << 9) + lane * 8);
    short8_t a[2];
#pragma unroll
    for (int rt = 0; rt < 2; ++rt)
      a[rt] = *(const short8_t*)(actin + (rt * 32 + n32) * Sin + kl);
#pragma unroll
    for (int ct = 0; ct < CT; ++ct)
#pragma unroll
      for (int rt = 0; rt < 2; ++rt)
        acc[rt][ct] = __builtin_amdgcn_mfma_f32_32x32x16_bf16(a[rt], b[ct], acc[rt][ct], 0, 0, 0);
  }
}

// C/D layout (verified m74/m101): col = lane&31, row = (reg&3)+8*(reg>>2)+4*(lane>>5)
template <int CT, int ACTF>
__device__ __forceinline__ void epi32(f32x16 (&acc)[2][CT], short* actout, int Sout,
                                      const float* __restrict__ bias, int c0, int n32, int q32) {
#pragma unroll
  for (int ct = 0; ct < CT; ++ct) {
    const int c = c0 + ct * 32 + n32;
    const float bv = bias[c];
#pragma unroll
    for (int rt = 0; rt < 2; ++rt)
#pragma unroll
      for (int reg = 0; reg < 16; ++reg) {
        const int r = rt * 32 + (reg & 3) + 8 * (reg >> 2) + 4 * q32;
        float v = acc[rt][ct][reg] + bv;
        if (ACTF == 1) v = fmaxf(v, 0.f);
        actout[r * Sout + c] = f2bf(v);
      }
  }
}

template <int K, int N, int ACTF>
__device__ __forceinline__ void layer32(const short* actin, int Sin, short* actout, int Sout,
                                        const short* __restrict__ wsB,
                                        const float* __restrict__ bias,
                                        int wv, int lane) {
  constexpr int CT = N / 128;          // used only with N=128 -> CT=1
  const int cb0 = wv * CT;
  const int n32 = lane & 31, q32 = lane >> 5;
  f32x16 acc[2][CT];
#pragma unroll
  for (int rt = 0; rt < 2; ++rt)
#pragma unroll
    for (int ct = 0; ct < CT; ++ct) acc[rt][ct] = (f32x16)(0.f);
  gemm32<K / 16, K / 16, CT>(actin, Sin, wsB, 0, cb0, acc, lane);
  epi32<CT, ACTF>(acc, actout, Sout, bias, cb0 * 32, n32, q32);
}

// mid-L1: K=128 -> N=256 ReLU, A -> B2, two CT=1 passes (acc stays 32 regs).
// Pass h covers cols h*128 + wv*32; disjoint across waves+passes, all read A.
__device__ __forceinline__ void mid1_256(const short* A, short* B2,
                                         const short* __restrict__ ws1,
                                         const float* __restrict__ b1,
                                         int wv, int lane) {
  const int n32 = lane & 31, q32 = lane >> 5;
#pragma unroll
  for (int h = 0; h < 2; ++h) {
    f32x16 acc[2][1];
    acc[0][0] = (f32x16)(0.f); acc[1][0] = (f32x16)(0.f);
    gemm32<8, 8, 1>(A, 136, ws1, 0, h * 4 + wv, acc, lane);
    epi32<1, 1>(acc, B2, 264, b1, (h * 4 + wv) * 32, n32, q32);
  }
}

// ---- input streaming: 64 rows x 128 cols fp32 per chunk --------------------
__device__ __forceinline__ void stage_load(const float* __restrict__ src, int row0, int colbase,
                                           int tid, float4 (&v)[8]) {
  const int c4 = tid & 31, rb = tid >> 5;
#pragma unroll
  for (int it = 0; it < 8; ++it)
    v[it] = *(const float4*)(src + (size_t)(row0 + rb + it * 8) * 256 + colbase + c4 * 4);
}

// mmode: 0 none, 1 init maskacc, 2 accumulate
__device__ __forceinline__ void stage_store(short* Pb, int tid, const float4 (&v)[8],
                                            float* maskacc, int mmode) {
  const int c4 = tid & 31, rb = tid >> 5;
#pragma unroll
  for (int it = 0; it < 8; ++it) {
    const int r = rb + it * 8;
    short4 pk; pk.x = f2bf(v[it].x); pk.y = f2bf(v[it].y); pk.z = f2bf(v[it].z); pk.w = f2bf(v[it].w);
    *(short4*)(Pb + r * 136 + c4 * 4) = pk;
    if (mmode) {
      float s = v[it].x + v[it].y + v[it].z + v[it].w;
      s += __shfl_down(s, 16, 32);
      s += __shfl_down(s, 8, 32);
      s += __shfl_down(s, 4, 32);
      s += __shfl_down(s, 2, 32);
      s += __shfl_down(s, 1, 32);
      if (c4 == 0) {
        if (mmode == 1) maskacc[r] = s; else maskacc[r] += s;
      }
    }
  }
}

// Streamed first layer (N=128 out): chunks kc<splitc from src0, else src1.
template <int NCH, bool MASKA>
__device__ __forceinline__ void stream32(const float* __restrict__ src0,
                                         const float* __restrict__ src1, int splitc,
                                         const short* __restrict__ wsB,
                                         const float* __restrict__ bias,
                                         short* P, short* Aout, float* maskacc,
                                         int row0, int tid, int wv, int lane) {
  constexpr int KT16 = NCH * 8;
  const int n32 = lane & 31, q32 = lane >> 5;
  f32x16 acc[2][1];
  acc[0][0] = (f32x16)(0.f); acc[1][0] = (f32x16)(0.f);
  float4 v[8];
  stage_load(src0, row0, 0, tid, v);
  stage_store(P, tid, v, maskacc, MASKA ? 1 : 0);
  __syncthreads();
#pragma unroll
  for (int kc = 0; kc < NCH; ++kc) {
    if (kc + 1 < NCH) {
      const bool lo = (kc + 1 < splitc);
      stage_load(lo ? src0 : src1, row0, (lo ? kc + 1 : kc + 1 - splitc) * 128, tid, v);
    }
    gemm32<KT16, 8, 1>(P + (kc & 1) * PE, 136, wsB, kc * 8, wv, acc, lane);
    if (kc + 1 < NCH)
      stage_store(P + ((kc + 1) & 1) * PE, tid, v, maskacc, (MASKA && kc + 1 < splitc) ? 2 : 0);
    __syncthreads();
  }
  epi32<1, 1>(acc, Aout, 136, bias, wv * 32, n32, q32);
}

// g3: K=128 N=256 sigmoid -> packed bf16 gate in VGPRs, two CT=1 passes.
// gate[rt][h][p] covers rows pair (r0,r0+1), col h*128 + wv*32 + n32.
__device__ __forceinline__ void gate_layer(const short* actin, const short* __restrict__ wsB,
                                           const float* __restrict__ bias,
                                           uint32_t (&gate)[2][2][8],
                                           int wv, int lane) {
  const int n32 = lane & 31;
#pragma unroll
  for (int h = 0; h < 2; ++h) {
    f32x16 acc[2][1];
    acc[0][0] = (f32x16)(0.f); acc[1][0] = (f32x16)(0.f);
    gemm32<8, 8, 1>(actin, 136, wsB, 0, h * 4 + wv, acc, lane);
    const float bv = bias[h * 128 + wv * 32 + n32];
#pragma unroll
    for (int rt = 0; rt < 2; ++rt)
#pragma unroll
      for (int p = 0; p < 8; ++p) {
        const float g0 = 1.f / (1.f + __expf(-(acc[rt][0][2 * p] + bv)));
        const float g1 = 1.f / (1.f + __expf(-(acc[rt][0][2 * p + 1] + bv)));
        gate[rt][h][p] = ((uint32_t)(uint16_t)f2bf(g1) << 16) | (uint32_t)(uint16_t)f2bf(g0);
      }
  }
}

// o3: K=128 N=256 in two CT=1 passes, fused mask*gate*val reduce + atomicAdd.
__device__ __forceinline__ void final32(const short* actin, const short* __restrict__ wsB,
                                        const float* __restrict__ bias,
                                        const uint32_t (&gate)[2][2][8],
                                        const float* maskacc, float* __restrict__ out,
                                        int row0, int wv, int lane) {
  const int n32 = lane & 31, q32 = lane >> 5;
  const int b = row0 >> 8;       // 64 | 256, 4 WGs per batch
#pragma unroll
  for (int h = 0; h < 2; ++h) {
    f32x16 acc[2][1];
    acc[0][0] = (f32x16)(0.f); acc[1][0] = (f32x16)(0.f);
    gemm32<8, 8, 1>(actin, 136, wsB, 0, h * 4 + wv, acc, lane);
    const int c = h * 128 + wv * 32 + n32;
    const float bv = bias[c];
    float s = 0.f;
#pragma unroll
    for (int rt = 0; rt < 2; ++rt)
#pragma unroll
      for (int p = 0; p < 8; ++p) {
        const int r0 = rt * 32 + ((2 * p) & 3) + 8 * (p >> 1) + 4 * q32;  // reg=2p
        const float g0 = bf2f((short)(gate[rt][h][p] & 0xFFFF));
        const float g1 = bf2f((short)(gate[rt][h][p] >> 16));
        const float v0 = acc[rt][0][2 * p] + bv;
        const float v1 = acc[rt][0][2 * p + 1] + bv;
        if (maskacc[r0] > 0.f)     s += g0 * v0;
        if (maskacc[r0 + 1] > 0.f) s += g1 * v1;
      }
    s += __shfl_down(s, 32);
    if (lane < 32) atomicAdd(out + b * 256 + c, s);
  }
}

__global__ __launch_bounds__(NTHR, 3)
void readout_main(const float* __restrict__ h0, const float* __restrict__ hT,
                  const short* __restrict__ ws,
                  const float* __restrict__ gb0, const float* __restrict__ gb1,
                  const float* __restrict__ gb2, const float* __restrict__ gb3,
                  const float* __restrict__ ob0, const float* __restrict__ ob1,
                  const float* __restrict__ ob2, const float* __restrict__ ob3,
                  float* __restrict__ out) {
  __shared__ __align__(16) char smem[LDS_TOTAL];
  short* P  = (short*)(smem + OFF_P);
  short* B2 = (short*)(smem + OFF_P);      // [64][264], aliases P (disjoint lifetimes)
  short* A  = (short*)(smem + OFF_A);      // [64][136]
  float* maskacc = (float*)(smem + OFF_MASK);

  const int tid = threadIdx.x, lane = tid & 63, wv = tid >> 6;
  const int row0 = blockIdx.x * ROWS;
  uint32_t gate[2][2][8];

  // gate chain
  stream32<4, true>(h0, hT, 2, ws + 0, gb0, P, A, maskacc, row0, tid, wv, lane);
  __syncthreads();
  mid1_256(A, B2, ws + 65536, gb1, wv, lane);
  __syncthreads();
  layer32<256, 128, 1>(B2, 264, A, 136, ws + 98304, gb2, wv, lane);
  __syncthreads();
  gate_layer(A, ws + 131072, gb3, gate, wv, lane);
  __syncthreads();
  // value chain (hT re-streamed, L3-warm)
  stream32<2, false>(hT, hT, 2, ws + 163840, ob0, P, A, maskacc, row0, tid, wv, lane);
  __syncthreads();
  mid1_256(A, B2, ws + 196608, ob1, wv, lane);
  __syncthreads();
  layer32<256, 128, 1>(B2, 264, A, 136, ws + 229376, ob2, wv, lane);
  __syncthreads();
  final32(A, ws + 262144, ob3, gate, maskacc, out, row0, wv, lane);
}

// ---- prep: weights fp32[K][N] -> bf16 fragment-ordered; zero out -----------
// ws elem off = layer_off + ((cb*(K/16) + ks)<<9) + lanei*8 + j
//   with n = cb*32 + (lanei&31), k = ks*16 + (lanei>>5)*8 + j.
__global__ void prep(const float* __restrict__ W0, const float* __restrict__ W1,
                     const float* __restrict__ W2, const float* __restrict__ W3,
                     const float* __restrict__ W4, const float* __restrict__ W5,
                     const float* __restrict__ W6, const float* __restrict__ W7,
                     short* __restrict__ ws, float* __restrict__ out) {
  const int l = blockIdx.y;
  const int le = blockIdx.x * 256 + threadIdx.x;    // < 65536
  if (l == 1) { out[le] = 0.f; out[le + 65536] = 0.f; }
  int K, N, off; const float* W;
  switch (l) {
    case 0:  K = 512; N = 128; off = 0;      W = W0; break;
    case 1:  K = 128; N = 256; off = 65536;  W = W1; break;
    case 2:  K = 256; N = 128; off = 98304;  W = W2; break;
    case 3:  K = 128; N = 256; off = 131072; W = W3; break;
    case 4:  K = 256; N = 128; off = 163840; W = W4; break;
    case 5:  K = 128; N = 256; off = 196608; W = W5; break;
    case 6:  K = 256; N = 128; off = 229376; W = W6; break;
    default: K = 128; N = 256; off = 262144; W = W7; break;
  }
  if (le >= K * N) return;
  const int j = le & 7;
  const int lanei = (le >> 3) & 63;
  const int blk = le >> 9;
  const int kt16 = K >> 4;
  const int ks = blk % kt16, cb = blk / kt16;
  const int n = cb * 32 + (lanei & 31);
  const int k = ks * 16 + (lanei >> 5) * 8 + j;
  ws[off + le] = f2bf(W[k * N + n]);    // coalesced write, gathered read
}

extern "C" void kernel_launch(void* const* d_in, const int* in_sizes, int n_in,
                              void* d_out, int out_size, void* d_ws, size_t ws_size,
                              hipStream_t stream) {
  const float* h0  = (const float*)d_in[0];
  const float* hT  = (const float*)d_in[1];
  const float* gW0 = (const float*)d_in[2];  const float* gb0 = (const float*)d_in[3];
  const float* gW1 = (const float*)d_in[4];  const float* gb1 = (const float*)d_in[5];
  const float* gW2 = (const float*)d_in[6];  const float* gb2 = (const float*)d_in[7];
  const float* gW3 = (const float*)d_in[8];  const float* gb3 = (const float*)d_in[9];
  const float* oW0 = (const float*)d_in[10]; const float* ob0 = (const float*)d_in[11];
  const float* oW1 = (const float*)d_in[12]; const float* ob1 = (const float*)d_in[13];
  const float* oW2 = (const float*)d_in[14]; const float* ob2 = (const float*)d_in[15];
  const float* oW3 = (const float*)d_in[16]; const float* ob3 = (const float*)d_in[17];
  float* out = (float*)d_out;
  short* ws  = (short*)d_ws;   // 589824 B

  prep<<<dim3(256, 8), 256, 0, stream>>>(gW0, gW1, gW2, gW3, oW0, oW1, oW2, oW3, ws, out);
  readout_main<<<NWG, NTHR, 0, stream>>>(h0, hT, ws,
                                         gb0, gb1, gb2, gb3,
                                         ob0, ob1, ob2, ob3, out);
}